// Round 12
// baseline (1486.325 us; speedup 1.0000x reference)
//
#include <hip/hip_runtime.h>
#include <hip/hip_bf16.h>
#include <stdint.h>
#include <stddef.h>

#define T_STEPS 128
#define F_IN 9
#define HID 128
#define OUT_N 12
#define XROW (T_STEPS * F_IN)  // 1152
#define BATCH 16384

typedef __attribute__((ext_vector_type(8))) short bf16x8;
typedef __attribute__((ext_vector_type(4))) float f32x4;

#define MFMA16(a, b, c) __builtin_amdgcn_mfma_f32_16x16x32_bf16((a), (b), (c), 0, 0, 0)

// manual RNE (prep kernels — cold path)
__device__ __forceinline__ short f2bf(float f) {
  union { float f; uint32_t u; } v; v.f = f;
  return (short)((v.u + 0x7fffu + ((v.u >> 16) & 1u)) >> 16);  // RNE
}
// hot-path conversion via the HW converter (RNE, bit-identical to f2bf)
__device__ __forceinline__ short f2bf_hw(float f) {
  __hip_bfloat16 h = __float2bfloat16(f);
  union { __hip_bfloat16 h; short s; } u; u.h = h;
  return u.s;
}
__device__ __forceinline__ float frcp(float x) { return __builtin_amdgcn_rcpf(x); }
__device__ __forceinline__ float fexp2(float x) { return __builtin_amdgcn_exp2f(x); }
__device__ __forceinline__ float tanh_f(float x) {  // plain-arg tanh (for tanh(c))
  return 1.0f - 2.0f * frcp(1.0f + fexp2(2.8853900817779268f * x));
}

// ---------------- prep 0: x [B,T,9] f32 -> xbf [t][row][16] bf16 (padded) ----------------
__global__ void prep_x(const float* __restrict__ x, short* __restrict__ xbf) {
  int idx = blockIdx.x * blockDim.x + threadIdx.x;  // 0 .. B*T-1, row fastest (coalesced writes)
  int row = idx & (BATCH - 1), t = idx >> 14;
  const float* xp = x + (size_t)row * XROW + t * F_IN;
  short v[16];
#pragma unroll
  for (int j = 0; j < F_IN; ++j) v[j] = f2bf(xp[j]);
#pragma unroll
  for (int j = F_IN; j < 16; ++j) v[j] = 0;
  int4* dst = (int4*)(xbf + (size_t)idx * 16);
  dst[0] = ((const int4*)v)[0];
  dst[1] = ((const int4*)v)[1];
}

// ---------------- prep 1: W0x = Wih0 @ W_in  [512,9] -> B-frags; combined biases ----------------
__global__ void prep_w0x(const float* __restrict__ W_in, const float* __restrict__ b_in,
                         const float* __restrict__ Wih0, const float* __restrict__ bih0,
                         const float* __restrict__ bhh0, const float* __restrict__ bih1,
                         const float* __restrict__ bhh1,
                         short* __restrict__ w0xf, float* __restrict__ b0x, float* __restrict__ b1) {
  int tid = threadIdx.x;             // 0..511
  int nt = tid >> 4, hl = tid & 15;  // global ntile, col-in-tile
  int w = nt >> 2, g = nt & 3;       // wave slice, gate
  int n = g * 128 + w * 16 + hl;     // original row of Wih0 (PyTorch i,f,g,o order)
  float wacc[F_IN];
#pragma unroll
  for (int f = 0; f < F_IN; ++f) wacc[f] = 0.f;
  float bacc = 0.f;
  for (int h = 0; h < HID; ++h) {
    float wv = Wih0[n * HID + h];
    bacc += wv * b_in[h];
#pragma unroll
    for (int f = 0; f < F_IN; ++f) wacc[f] += wv * W_in[h * F_IN + f];
  }
  b0x[n] = bacc + bih0[n] + bhh0[n];
  b1[n] = bih1[n] + bhh1[n];
#pragma unroll
  for (int k = 0; k < 32; ++k) {  // one K=32 tile, f<9 real, rest zero
    int quad = k >> 3, j = k & 7;
    w0xf[((w * 4 + g) * 64 + quad * 16 + hl) * 8 + j] = (k < F_IN) ? f2bf(wacc[k]) : (short)0;
  }
}

// ---------------- prep 2: per-wave-contiguous frag layouts ----------------
__global__ void prep_wrec(const float* __restrict__ Whh0, const float* __restrict__ Wih1,
                          const float* __restrict__ Whh1,
                          short* __restrict__ whh0f, short* __restrict__ w1f) {
  int gt = blockIdx.x * blockDim.x + threadIdx.x;  // 0..6143
  if (gt < 2048) {
    int kt = gt >> 9, rr = gt & 511;
    int nt = rr >> 4, hl = rr & 15;
    int w = nt >> 2, g = nt & 3;
    int n = g * 128 + w * 16 + hl;
#pragma unroll
    for (int k = 0; k < 32; ++k) {
      int quad = k >> 3, j = k & 7;
      whh0f[((w * 16 + kt * 4 + g) * 64 + quad * 16 + hl) * 8 + j] =
          f2bf(Whh0[n * HID + kt * 32 + k]);
    }
  } else {
    int g2 = gt - 2048;
    int kt = g2 >> 9, rr = g2 & 511;  // kt 0..7: k<128 -> Wih1, else Whh1
    int nt = rr >> 4, hl = rr & 15;
    int w = nt >> 2, g = nt & 3;
    int n = g * 128 + w * 16 + hl;
#pragma unroll
    for (int k = 0; k < 32; ++k) {
      int quad = k >> 3, j = k & 7;
      int kg = kt * 32 + k;
      float v = (kg < HID) ? Wih1[n * HID + kg] : Whh1[n * HID + kg - HID];
      w1f[((w * 32 + kt * 4 + g) * 64 + quad * 16 + hl) * 8 + j] = f2bf(v);
    }
  }
}

// ===================== ROUND-21: anti-phase wave scheduling =====================
// r11 counters: VALUBusy 61.0 + MfmaUtil 34.5 = 95.5% — the two pipes run SERIALLY
// because the 2 waves/SIMD are barrier-synced copies of the same program: both enter
// the MFMA region together, then both enter the trans-heavy cell region together.
// m114 (learn_hip) proved MFMA-waves and VALU-waves co-schedule fully (time = max).
// Phase0(t) and phase1(t-1) are order-independent (both read only barrier-published
// buffers; writes disjoint), so HALF the waves run [phase1 -> phase0] and half
// [phase0 -> phase1]: each wave's trans burst overlaps its SIMD-mate's MFMA burst.
// flip = (w&1)^((w>>2)&1) anti-phases the pair under BOTH plausible wave->SIMD
// mappings (round-robin pairs {w,w+4} differ in bit2; consecutive pairs in bit0).
// In the flipped path the x-MFMA group moves to the END of phase0 so x-loads keep
// MFMA cover. Barrier counts identical in both branches (legal divergent barrier).

// ---- order A (r11's): phase1(t-1) then phase0(t); x-group first in phase0 ----
__device__ __forceinline__ void lstm_step_p1p0(
    int t, const short* __restrict__ xpl, const short* __restrict__ wp0,
    const short* __restrict__ wph, const short* __restrict__ wp1,
    const float* sb0, const float* sb1, float* c0buf, float* c1buf,
    const short* h0r, short* h0w, const short* h1r, short* h1w,
    int tid, int lane, int wr_off, int quad) {
  const f32x4 z4 = {0.f, 0.f, 0.f, 0.f};
  const short* xt = xpl + (size_t)t * 262144;

  // ---- phase1(t-1) MFMA: acc1 = h0_{t-1}@Wih1^T + h1_{t-2}@Whh1^T (all 4 mt) ----
  f32x4 acc1[4][4];
  {
    const short* wb = wp1;
    bf16x8 b0_ = *(const bf16x8*)(wb);
    bf16x8 b1_ = *(const bf16x8*)(wb + 512);
    bf16x8 b2_ = *(const bf16x8*)(wb + 1024);
    bf16x8 b3_ = *(const bf16x8*)(wb + 1536);
#pragma unroll
    for (int mt = 0; mt < 4; ++mt) {
      bf16x8 af = *(const bf16x8*)(h0r + ((mt * 4 + 0) * 64 + lane) * 8);
      acc1[mt][0] = MFMA16(af, b0_, z4);
      acc1[mt][1] = MFMA16(af, b1_, z4);
      acc1[mt][2] = MFMA16(af, b2_, z4);
      acc1[mt][3] = MFMA16(af, b3_, z4);
    }
  }
#pragma clang loop unroll_count(3)
  for (int kt = 1; kt < 4; ++kt) {  // rest of Wih1, A = h0_{t-1}
    const short* wb = wp1 + kt * 2048;
    bf16x8 b0_ = *(const bf16x8*)(wb);
    bf16x8 b1_ = *(const bf16x8*)(wb + 512);
    bf16x8 b2_ = *(const bf16x8*)(wb + 1024);
    bf16x8 b3_ = *(const bf16x8*)(wb + 1536);
#pragma unroll
    for (int mt = 0; mt < 4; ++mt) {
      bf16x8 af = *(const bf16x8*)(h0r + ((mt * 4 + kt) * 64 + lane) * 8);
      acc1[mt][0] = MFMA16(af, b0_, acc1[mt][0]);
      acc1[mt][1] = MFMA16(af, b1_, acc1[mt][1]);
      acc1[mt][2] = MFMA16(af, b2_, acc1[mt][2]);
      acc1[mt][3] = MFMA16(af, b3_, acc1[mt][3]);
    }
  }
#pragma clang loop unroll_count(2)
  for (int kt = 0; kt < 4; ++kt) {  // Whh1, A = h1_{t-2}
    const short* wb = wp1 + (kt + 4) * 2048;
    bf16x8 b0_ = *(const bf16x8*)(wb);
    bf16x8 b1_ = *(const bf16x8*)(wb + 512);
    bf16x8 b2_ = *(const bf16x8*)(wb + 1024);
    bf16x8 b3_ = *(const bf16x8*)(wb + 1536);
#pragma unroll
    for (int mt = 0; mt < 4; ++mt) {
      bf16x8 af = *(const bf16x8*)(h1r + ((mt * 4 + kt) * 64 + lane) * 8);
      acc1[mt][0] = MFMA16(af, b0_, acc1[mt][0]);
      acc1[mt][1] = MFMA16(af, b1_, acc1[mt][1]);
      acc1[mt][2] = MFMA16(af, b2_, acc1[mt][2]);
      acc1[mt][3] = MFMA16(af, b3_, acc1[mt][3]);
    }
  }
  // cell 1 (for step t-1): c1 state in LDS
#pragma unroll
  for (int mt = 0; mt < 4; ++mt) {
    f32x4 cp = *(const f32x4*)(c1buf + 4 * (mt * 512 + tid));
    f32x4 cn;
#pragma unroll
    for (int r = 0; r < 4; ++r) {
      float gi = frcp(1.0f + fexp2(fmaf(-1.4426950408889634f, acc1[mt][0][r], sb1[0])));
      float gf = frcp(1.0f + fexp2(fmaf(-1.4426950408889634f, acc1[mt][1][r], sb1[1])));
      float gg = 1.0f - 2.0f * frcp(1.0f + fexp2(fmaf(2.8853900817779268f, acc1[mt][2][r], sb1[2])));
      float go = frcp(1.0f + fexp2(fmaf(-1.4426950408889634f, acc1[mt][3][r], sb1[3])));
      cn[r] = gf * cp[r] + gi * gg;
      float hn = go * tanh_f(cn[r]);
      h1w[mt * 2048 + r * 8 + wr_off] = f2bf_hw(hn);
    }
    *(f32x4*)(c1buf + 4 * (mt * 512 + tid)) = cn;
  }
  // ---- phase0(t): acc0 = x_t@W0x^T + h0_{t-1}@Whh0^T ----
  f32x4 acc0[4][4];
  {
    bf16x8 b0_ = *(const bf16x8*)(wp0);
    bf16x8 b1_ = *(const bf16x8*)(wp0 + 512);
    bf16x8 b2_ = *(const bf16x8*)(wp0 + 1024);
    bf16x8 b3_ = *(const bf16x8*)(wp0 + 1536);
#pragma unroll
    for (int mt = 0; mt < 4; ++mt) {
      bf16x8 xf = {0, 0, 0, 0, 0, 0, 0, 0};
      if (quad < 2) xf = *(const bf16x8*)(xt + mt * 256);
      acc0[mt][0] = MFMA16(xf, b0_, z4);
      acc0[mt][1] = MFMA16(xf, b1_, z4);
      acc0[mt][2] = MFMA16(xf, b2_, z4);
      acc0[mt][3] = MFMA16(xf, b3_, z4);
    }
  }
#pragma clang loop unroll_count(2)
  for (int kt = 0; kt < 4; ++kt) {
    const short* wb = wph + kt * 2048;
    bf16x8 b0_ = *(const bf16x8*)(wb);
    bf16x8 b1_ = *(const bf16x8*)(wb + 512);
    bf16x8 b2_ = *(const bf16x8*)(wb + 1024);
    bf16x8 b3_ = *(const bf16x8*)(wb + 1536);
#pragma unroll
    for (int mt = 0; mt < 4; ++mt) {
      bf16x8 af = *(const bf16x8*)(h0r + ((mt * 4 + kt) * 64 + lane) * 8);
      acc0[mt][0] = MFMA16(af, b0_, acc0[mt][0]);
      acc0[mt][1] = MFMA16(af, b1_, acc0[mt][1]);
      acc0[mt][2] = MFMA16(af, b2_, acc0[mt][2]);
      acc0[mt][3] = MFMA16(af, b3_, acc0[mt][3]);
    }
  }
  // cell 0: c0 state in LDS (c0buf aliases h1fp)
#pragma unroll
  for (int mt = 0; mt < 4; ++mt) {
    f32x4 cp = *(const f32x4*)(c0buf + 4 * (mt * 512 + tid));
    f32x4 cn;
#pragma unroll
    for (int r = 0; r < 4; ++r) {
      float gi = frcp(1.0f + fexp2(fmaf(-1.4426950408889634f, acc0[mt][0][r], sb0[0])));
      float gf = frcp(1.0f + fexp2(fmaf(-1.4426950408889634f, acc0[mt][1][r], sb0[1])));
      float gg = 1.0f - 2.0f * frcp(1.0f + fexp2(fmaf(2.8853900817779268f, acc0[mt][2][r], sb0[2])));
      float go = frcp(1.0f + fexp2(fmaf(-1.4426950408889634f, acc0[mt][3][r], sb0[3])));
      cn[r] = gf * cp[r] + gi * gg;
      float hn = go * tanh_f(cn[r]);
      h0w[mt * 2048 + r * 8 + wr_off] = f2bf_hw(hn);
    }
    *(f32x4*)(c0buf + 4 * (mt * 512 + tid)) = cn;
  }
  __syncthreads();  // the ONE barrier: publishes h0_t and h1_{t-1}
}

// ---- order B (flipped): phase0(t) then phase1(t-1); Whh0 groups first, x-group last ----
__device__ __forceinline__ void lstm_step_p0p1(
    int t, const short* __restrict__ xpl, const short* __restrict__ wp0,
    const short* __restrict__ wph, const short* __restrict__ wp1,
    const float* sb0, const float* sb1, float* c0buf, float* c1buf,
    const short* h0r, short* h0w, const short* h1r, short* h1w,
    int tid, int lane, int wr_off, int quad) {
  const f32x4 z4 = {0.f, 0.f, 0.f, 0.f};
  const short* xt = xpl + (size_t)t * 262144;
  // x loads issued first; used only after the 4 Whh0 groups (latency cover)
  bf16x8 xf[4];
#pragma unroll
  for (int mt = 0; mt < 4; ++mt) {
    bf16x8 v = {0, 0, 0, 0, 0, 0, 0, 0};
    if (quad < 2) v = *(const bf16x8*)(xt + mt * 256);
    xf[mt] = v;
  }
  // ---- phase0(t): Whh0 first (kt=0 inits), x-group last ----
  f32x4 acc0[4][4];
  {
    const short* wb = wph;  // kt = 0
    bf16x8 b0_ = *(const bf16x8*)(wb);
    bf16x8 b1_ = *(const bf16x8*)(wb + 512);
    bf16x8 b2_ = *(const bf16x8*)(wb + 1024);
    bf16x8 b3_ = *(const bf16x8*)(wb + 1536);
#pragma unroll
    for (int mt = 0; mt < 4; ++mt) {
      bf16x8 af = *(const bf16x8*)(h0r + ((mt * 4 + 0) * 64 + lane) * 8);
      acc0[mt][0] = MFMA16(af, b0_, z4);
      acc0[mt][1] = MFMA16(af, b1_, z4);
      acc0[mt][2] = MFMA16(af, b2_, z4);
      acc0[mt][3] = MFMA16(af, b3_, z4);
    }
  }
#pragma clang loop unroll_count(3)
  for (int kt = 1; kt < 4; ++kt) {
    const short* wb = wph + kt * 2048;
    bf16x8 b0_ = *(const bf16x8*)(wb);
    bf16x8 b1_ = *(const bf16x8*)(wb + 512);
    bf16x8 b2_ = *(const bf16x8*)(wb + 1024);
    bf16x8 b3_ = *(const bf16x8*)(wb + 1536);
#pragma unroll
    for (int mt = 0; mt < 4; ++mt) {
      bf16x8 af = *(const bf16x8*)(h0r + ((mt * 4 + kt) * 64 + lane) * 8);
      acc0[mt][0] = MFMA16(af, b0_, acc0[mt][0]);
      acc0[mt][1] = MFMA16(af, b1_, acc0[mt][1]);
      acc0[mt][2] = MFMA16(af, b2_, acc0[mt][2]);
      acc0[mt][3] = MFMA16(af, b3_, acc0[mt][3]);
    }
  }
  {  // x-group accumulates last
    bf16x8 b0_ = *(const bf16x8*)(wp0);
    bf16x8 b1_ = *(const bf16x8*)(wp0 + 512);
    bf16x8 b2_ = *(const bf16x8*)(wp0 + 1024);
    bf16x8 b3_ = *(const bf16x8*)(wp0 + 1536);
#pragma unroll
    for (int mt = 0; mt < 4; ++mt) {
      acc0[mt][0] = MFMA16(xf[mt], b0_, acc0[mt][0]);
      acc0[mt][1] = MFMA16(xf[mt], b1_, acc0[mt][1]);
      acc0[mt][2] = MFMA16(xf[mt], b2_, acc0[mt][2]);
      acc0[mt][3] = MFMA16(xf[mt], b3_, acc0[mt][3]);
    }
  }
  // cell 0
#pragma unroll
  for (int mt = 0; mt < 4; ++mt) {
    f32x4 cp = *(const f32x4*)(c0buf + 4 * (mt * 512 + tid));
    f32x4 cn;
#pragma unroll
    for (int r = 0; r < 4; ++r) {
      float gi = frcp(1.0f + fexp2(fmaf(-1.4426950408889634f, acc0[mt][0][r], sb0[0])));
      float gf = frcp(1.0f + fexp2(fmaf(-1.4426950408889634f, acc0[mt][1][r], sb0[1])));
      float gg = 1.0f - 2.0f * frcp(1.0f + fexp2(fmaf(2.8853900817779268f, acc0[mt][2][r], sb0[2])));
      float go = frcp(1.0f + fexp2(fmaf(-1.4426950408889634f, acc0[mt][3][r], sb0[3])));
      cn[r] = gf * cp[r] + gi * gg;
      float hn = go * tanh_f(cn[r]);
      h0w[mt * 2048 + r * 8 + wr_off] = f2bf_hw(hn);
    }
    *(f32x4*)(c0buf + 4 * (mt * 512 + tid)) = cn;
  }
  // ---- phase1(t-1): acc1 = h0_{t-1}@Wih1^T + h1_{t-2}@Whh1^T ----
  f32x4 acc1[4][4];
  {
    const short* wb = wp1;
    bf16x8 b0_ = *(const bf16x8*)(wb);
    bf16x8 b1_ = *(const bf16x8*)(wb + 512);
    bf16x8 b2_ = *(const bf16x8*)(wb + 1024);
    bf16x8 b3_ = *(const bf16x8*)(wb + 1536);
#pragma unroll
    for (int mt = 0; mt < 4; ++mt) {
      bf16x8 af = *(const bf16x8*)(h0r + ((mt * 4 + 0) * 64 + lane) * 8);
      acc1[mt][0] = MFMA16(af, b0_, z4);
      acc1[mt][1] = MFMA16(af, b1_, z4);
      acc1[mt][2] = MFMA16(af, b2_, z4);
      acc1[mt][3] = MFMA16(af, b3_, z4);
    }
  }
#pragma clang loop unroll_count(3)
  for (int kt = 1; kt < 4; ++kt) {
    const short* wb = wp1 + kt * 2048;
    bf16x8 b0_ = *(const bf16x8*)(wb);
    bf16x8 b1_ = *(const bf16x8*)(wb + 512);
    bf16x8 b2_ = *(const bf16x8*)(wb + 1024);
    bf16x8 b3_ = *(const bf16x8*)(wb + 1536);
#pragma unroll
    for (int mt = 0; mt < 4; ++mt) {
      bf16x8 af = *(const bf16x8*)(h0r + ((mt * 4 + kt) * 64 + lane) * 8);
      acc1[mt][0] = MFMA16(af, b0_, acc1[mt][0]);
      acc1[mt][1] = MFMA16(af, b1_, acc1[mt][1]);
      acc1[mt][2] = MFMA16(af, b2_, acc1[mt][2]);
      acc1[mt][3] = MFMA16(af, b3_, acc1[mt][3]);
    }
  }
#pragma clang loop unroll_count(2)
  for (int kt = 0; kt < 4; ++kt) {
    const short* wb = wp1 + (kt + 4) * 2048;
    bf16x8 b0_ = *(const bf16x8*)(wb);
    bf16x8 b1_ = *(const bf16x8*)(wb + 512);
    bf16x8 b2_ = *(const bf16x8*)(wb + 1024);
    bf16x8 b3_ = *(const bf16x8*)(wb + 1536);
#pragma unroll
    for (int mt = 0; mt < 4; ++mt) {
      bf16x8 af = *(const bf16x8*)(h1r + ((mt * 4 + kt) * 64 + lane) * 8);
      acc1[mt][0] = MFMA16(af, b0_, acc1[mt][0]);
      acc1[mt][1] = MFMA16(af, b1_, acc1[mt][1]);
      acc1[mt][2] = MFMA16(af, b2_, acc1[mt][2]);
      acc1[mt][3] = MFMA16(af, b3_, acc1[mt][3]);
    }
  }
  // cell 1
#pragma unroll
  for (int mt = 0; mt < 4; ++mt) {
    f32x4 cp = *(const f32x4*)(c1buf + 4 * (mt * 512 + tid));
    f32x4 cn;
#pragma unroll
    for (int r = 0; r < 4; ++r) {
      float gi = frcp(1.0f + fexp2(fmaf(-1.4426950408889634f, acc1[mt][0][r], sb1[0])));
      float gf = frcp(1.0f + fexp2(fmaf(-1.4426950408889634f, acc1[mt][1][r], sb1[1])));
      float gg = 1.0f - 2.0f * frcp(1.0f + fexp2(fmaf(2.8853900817779268f, acc1[mt][2][r], sb1[2])));
      float go = frcp(1.0f + fexp2(fmaf(-1.4426950408889634f, acc1[mt][3][r], sb1[3])));
      cn[r] = gf * cp[r] + gi * gg;
      float hn = go * tanh_f(cn[r]);
      h1w[mt * 2048 + r * 8 + wr_off] = f2bf_hw(hn);
    }
    *(f32x4*)(c1buf + 4 * (mt * 512 + tid)) = cn;
  }
  __syncthreads();  // the ONE barrier: publishes h0_t and h1_{t-1}
}

// ---------------- main: 256 blocks x 512 thr, M=64/block (ONE round) ----------------
// Established facts: 512-thr + no attribute -> allocator follows LDS model (124 regs,
// no spill); occupancy fixed at 2 waves/SIMD; LDS 134144 B -> 1-WG compiler model.
// TRIPWIRE: WRITE_SIZE >> 1 MB = spill => revert to r20.
__global__ void __launch_bounds__(512)
lstm_main(const short* __restrict__ xbf, const short* __restrict__ w0xf,
          const short* __restrict__ whh0f, const short* __restrict__ w1f,
          const float* __restrict__ b0x, const float* __restrict__ b1,
          const float* __restrict__ Wout, const float* __restrict__ bout,
          float* __restrict__ out) {
  // Each h buffer: [4 mt][4 kt][64 lane][8] shorts = 8192 shorts (16 KB).
  __shared__ short h0a[8192], h0b[8192], h1a[8192], h1b[8192];  // 64 KB
  __shared__ float h1fp_c0[64 * HID];  // 32 KB: c0 state during loop, fp32 h1 at drain
  __shared__ float c1buf[64 * HID];    // 32 KB: c1 state [mt][tid] f32x4
  __shared__ float lg[64 * OUT_N];     // 3 KB logits
  // total LDS = 134144 B

  const int tid = threadIdx.x;
  const int w = tid >> 6, lane = tid & 63;   // w = wave id = weight/column slice 0..7
  const int quad = lane >> 4, c = lane & 15;
  const int rowbase = blockIdx.x * 64;

  {  // zero h buffers and c-state (h_{-1} = h_{-2} = c_{-1} = 0)
    for (int i = tid; i < 4096; i += 512) {
      ((int*)h0a)[i] = 0; ((int*)h0b)[i] = 0; ((int*)h1a)[i] = 0; ((int*)h1b)[i] = 0;
    }
    for (int i = tid; i < 8192; i += 512) { h1fp_c0[i] = 0.f; c1buf[i] = 0.f; }
  }

  // per-wave weight stream bases (t-invariant, lane offset folded in)
  const short* wp0 = w0xf + (w * 4) * 512 + lane * 8;    // 4 frags, stride 512 shorts
  const short* wph = whh0f + (w * 16) * 512 + lane * 8;  // 16 frags
  const short* wp1 = w1f + (w * 32) * 512 + lane * 8;    // 32 frags

  // x frag pointer: addr(t,mt) = ((t*16384 + rowbase + mt*16 + c) * 16 + (quad&1)*8) shorts
  const short* xpl = xbf + ((size_t)(rowbase + c) << 4) + ((quad & 1) << 3);

  // pre-scaled biases: gates i,f,o -> -1.4427*b (sigm); gate g(idx 2) -> +2.8854*b (tanh)
  float sb0[4], sb1[4];
#pragma unroll
  for (int g = 0; g < 4; ++g) {
    int n = g * 128 + w * 16 + c;
    float bv0 = b0x[n], bv1 = b1[n];
    sb0[g] = (g == 2) ? 2.8853900817779268f * bv0 : -1.4426950408889634f * bv0;
    sb1[g] = (g == 2) ? 2.8853900817779268f * bv1 : -1.4426950408889634f * bv1;
  }

  // writer constants: this lane's h column is hcol = w*16 + c
  const int kt_w = w >> 1;
  const int klocal = ((w & 1) << 4) + c;
  const int quadA = klocal >> 3;
  const int jA = klocal & 7;
  const int wr_off = (kt_w * 64 + quadA * 16 + quad * 4) * 8 + jA;  // + mt*2048 + r*8

  const f32x4 z4 = {0.f, 0.f, 0.f, 0.f};

  __syncthreads();

  // ================= prologue: phase0(t=0) -> h0a =================
  {
    f32x4 acc[4][4];
    {
      bf16x8 b0_ = *(const bf16x8*)(wp0);
      bf16x8 b1_ = *(const bf16x8*)(wp0 + 512);
      bf16x8 b2_ = *(const bf16x8*)(wp0 + 1024);
      bf16x8 b3_ = *(const bf16x8*)(wp0 + 1536);
#pragma unroll
      for (int mt = 0; mt < 4; ++mt) {
        bf16x8 xf = {0, 0, 0, 0, 0, 0, 0, 0};
        if (quad < 2) xf = *(const bf16x8*)(xpl + mt * 256);
        acc[mt][0] = MFMA16(xf, b0_, z4);
        acc[mt][1] = MFMA16(xf, b1_, z4);
        acc[mt][2] = MFMA16(xf, b2_, z4);
        acc[mt][3] = MFMA16(xf, b3_, z4);
      }
    }
    // h0_{-1} = 0: whh0 contribution is zero — skip the 4 kt groups entirely.
#pragma unroll
    for (int mt = 0; mt < 4; ++mt) {
      f32x4 cn;
#pragma unroll
      for (int r = 0; r < 4; ++r) {
        float gi = frcp(1.0f + fexp2(fmaf(-1.4426950408889634f, acc[mt][0][r], sb0[0])));
        float gg = 1.0f - 2.0f * frcp(1.0f + fexp2(fmaf(2.8853900817779268f, acc[mt][2][r], sb0[2])));
        float go = frcp(1.0f + fexp2(fmaf(-1.4426950408889634f, acc[mt][3][r], sb0[3])));
        cn[r] = gi * gg;  // c0_{-1} = 0
        float hn = go * tanh_f(cn[r]);
        h0a[mt * 2048 + r * 8 + wr_off] = f2bf_hw(hn);
      }
      *(f32x4*)(h1fp_c0 + 4 * (mt * 512 + tid)) = cn;
    }
  }
  __syncthreads();

  // ================= main loop: 63 static pairs + 1 tail, per-wave phase order ==========
  // parity: odd t reads {h0a,h1a} writes {h0b,h1b}; even t reads {h0b,h1b} writes {h0a,h1a}
  if (((w ^ (w >> 2)) & 1) == 0) {
#pragma clang loop unroll(disable)
    for (int t = 1; t < 127; t += 2) {
      lstm_step_p1p0(t,     xpl, wp0, wph, wp1, sb0, sb1, h1fp_c0, c1buf, h0a, h0b, h1a, h1b,
                     tid, lane, wr_off, quad);
      lstm_step_p1p0(t + 1, xpl, wp0, wph, wp1, sb0, sb1, h1fp_c0, c1buf, h0b, h0a, h1b, h1a,
                     tid, lane, wr_off, quad);
    }
    lstm_step_p1p0(127, xpl, wp0, wph, wp1, sb0, sb1, h1fp_c0, c1buf, h0a, h0b, h1a, h1b,
                   tid, lane, wr_off, quad);
  } else {
#pragma clang loop unroll(disable)
    for (int t = 1; t < 127; t += 2) {
      lstm_step_p0p1(t,     xpl, wp0, wph, wp1, sb0, sb1, h1fp_c0, c1buf, h0a, h0b, h1a, h1b,
                     tid, lane, wr_off, quad);
      lstm_step_p0p1(t + 1, xpl, wp0, wph, wp1, sb0, sb1, h1fp_c0, c1buf, h0b, h0a, h1b, h1a,
                     tid, lane, wr_off, quad);
    }
    lstm_step_p0p1(127, xpl, wp0, wph, wp1, sb0, sb1, h1fp_c0, c1buf, h0a, h0b, h1a, h1b,
                   tid, lane, wr_off, quad);
  }

  // ================= drain: phase1(t=127) -> fp32 h1 straight to LDS =================
  // after the tail step: h0b = h0(127), h1b = h1(126); c0 state is dead from here on,
  // so h1fp_c0 is reused as the fp32 h1 staging buffer.
  {
    f32x4 acc[4][4];
    {
      const short* wb = wp1;
      bf16x8 b0_ = *(const bf16x8*)(wb);
      bf16x8 b1_ = *(const bf16x8*)(wb + 512);
      bf16x8 b2_ = *(const bf16x8*)(wb + 1024);
      bf16x8 b3_ = *(const bf16x8*)(wb + 1536);
#pragma unroll
      for (int mt = 0; mt < 4; ++mt) {
        bf16x8 af = *(const bf16x8*)(h0b + ((mt * 4 + 0) * 64 + lane) * 8);
        acc[mt][0] = MFMA16(af, b0_, z4);
        acc[mt][1] = MFMA16(af, b1_, z4);
        acc[mt][2] = MFMA16(af, b2_, z4);
        acc[mt][3] = MFMA16(af, b3_, z4);
      }
    }
#pragma unroll
    for (int kt = 1; kt < 4; ++kt) {
      const short* wb = wp1 + kt * 2048;
      bf16x8 b0_ = *(const bf16x8*)(wb);
      bf16x8 b1_ = *(const bf16x8*)(wb + 512);
      bf16x8 b2_ = *(const bf16x8*)(wb + 1024);
      bf16x8 b3_ = *(const bf16x8*)(wb + 1536);
#pragma unroll
      for (int mt = 0; mt < 4; ++mt) {
        bf16x8 af = *(const bf16x8*)(h0b + ((mt * 4 + kt) * 64 + lane) * 8);
        acc[mt][0] = MFMA16(af, b0_, acc[mt][0]);
        acc[mt][1] = MFMA16(af, b1_, acc[mt][1]);
        acc[mt][2] = MFMA16(af, b2_, acc[mt][2]);
        acc[mt][3] = MFMA16(af, b3_, acc[mt][3]);
      }
    }
#pragma unroll
    for (int kt = 0; kt < 4; ++kt) {
      const short* wb = wp1 + (kt + 4) * 2048;
      bf16x8 b0_ = *(const bf16x8*)(wb);
      bf16x8 b1_ = *(const bf16x8*)(wb + 512);
      bf16x8 b2_ = *(const bf16x8*)(wb + 1024);
      bf16x8 b3_ = *(const bf16x8*)(wb + 1536);
#pragma unroll
      for (int mt = 0; mt < 4; ++mt) {
        bf16x8 af = *(const bf16x8*)(h1b + ((mt * 4 + kt) * 64 + lane) * 8);
        acc[mt][0] = MFMA16(af, b0_, acc[mt][0]);
        acc[mt][1] = MFMA16(af, b1_, acc[mt][1]);
        acc[mt][2] = MFMA16(af, b2_, acc[mt][2]);
        acc[mt][3] = MFMA16(af, b3_, acc[mt][3]);
      }
    }
    __syncthreads();  // all c0 reads done before h1fp overwrites
#pragma unroll
    for (int mt = 0; mt < 4; ++mt) {
      f32x4 cp = *(const f32x4*)(c1buf + 4 * (mt * 512 + tid));
#pragma unroll
      for (int r = 0; r < 4; ++r) {
        float gi = frcp(1.0f + fexp2(fmaf(-1.4426950408889634f, acc[mt][0][r], sb1[0])));
        float gf = frcp(1.0f + fexp2(fmaf(-1.4426950408889634f, acc[mt][1][r], sb1[1])));
        float gg = 1.0f - 2.0f * frcp(1.0f + fexp2(fmaf(2.8853900817779268f, acc[mt][2][r], sb1[2])));
        float go = frcp(1.0f + fexp2(fmaf(-1.4426950408889634f, acc[mt][3][r], sb1[3])));
        float cn = gf * cp[r] + gi * gg;
        float hn = go * tanh_f(cn);
        h1fp_c0[(mt * 16 + quad * 4 + r) * HID + w * 16 + c] = hn;
      }
    }
  }
  __syncthreads();  // h1fp complete before epilogue reads

  // ================= epilogue: logits = h1 @ Wout^T + bout, softmax over 12 =================
  {
    int row = tid >> 3, og = tid & 7;  // 64 rows x 8 threads
    for (int oc = og; oc < OUT_N; oc += 8) {
      float s = bout[oc];
      const float* wo = Wout + oc * HID;
      const float* hr = h1fp_c0 + row * HID;
#pragma unroll 8
      for (int k = 0; k < HID; ++k) s += hr[k] * wo[k];
      lg[row * OUT_N + oc] = s;
    }
  }
  __syncthreads();
  if (tid < 64) {
    int row = tid;
    float m = lg[row * OUT_N];
#pragma unroll
    for (int oc = 1; oc < OUT_N; ++oc) m = fmaxf(m, lg[row * OUT_N + oc]);
    float e[OUT_N];
    float s = 0.f;
#pragma unroll
    for (int oc = 0; oc < OUT_N; ++oc) {
      e[oc] = __expf(lg[row * OUT_N + oc] - m);
      s += e[oc];
    }
    float inv = 1.0f / s;
    float* orow = out + (size_t)(rowbase + row) * OUT_N;
#pragma unroll
    for (int oc = 0; oc < OUT_N; ++oc) orow[oc] = e[oc] * inv;
  }
}

extern "C" void kernel_launch(void* const* d_in, const int* in_sizes, int n_in,
                              void* d_out, int out_size, void* d_ws, size_t ws_size,
                              hipStream_t stream) {
  const float* x    = (const float*)d_in[0];
  const float* W_in = (const float*)d_in[1];
  const float* b_in = (const float*)d_in[2];
  const float* Wih0 = (const float*)d_in[3];
  const float* Whh0 = (const float*)d_in[4];
  const float* bih0 = (const float*)d_in[5];
  const float* bhh0 = (const float*)d_in[6];
  const float* Wih1 = (const float*)d_in[7];
  const float* Whh1 = (const float*)d_in[8];
  const float* bih1 = (const float*)d_in[9];
  const float* bhh1 = (const float*)d_in[10];
  const float* Wout = (const float*)d_in[11];
  const float* bout = (const float*)d_in[12];
  float* out = (float*)d_out;

  // workspace layout: frag-packed bf16 weights + combined biases (~420 KB) + xbf (64 MB)
  short* w0xf  = (short*)d_ws;            // 16384 shorts (32 KB)
  short* whh0f = w0xf + 16384;            // 65536 shorts (128 KB)
  short* w1f   = whh0f + 65536;           // 131072 shorts (256 KB)
  float* b0x   = (float*)(w1f + 131072);  // 512 f32
  float* b1    = b0x + 512;               // 512 f32
  short* xbf   = (short*)(b1 + 512);      // B*T*16 shorts = 64 MiB, 32B-aligned

  prep_x<<<(BATCH * T_STEPS) / 256, 256, 0, stream>>>(x, xbf);
  prep_w0x<<<1, 512, 0, stream>>>(W_in, b_in, Wih0, bih0, bhh0, bih1, bhh1, w0xf, b0x, b1);
  prep_wrec<<<12, 512, 0, stream>>>(Whh0, Wih1, Whh1, whh0f, w1f);
  lstm_main<<<256, 512, 0, stream>>>(xbf, w0xf, whh0f, w1f, b0x, b1, Wout, bout, out);
}

// Round 13
// 1181.939 us; speedup vs baseline: 1.2575x; 1.2575x over previous
//
#include <hip/hip_runtime.h>
#include <hip/hip_bf16.h>
#include <stdint.h>
#include <stddef.h>

#define T_STEPS 128
#define F_IN 9
#define HID 128
#define OUT_N 12
#define XROW (T_STEPS * F_IN)  // 1152
#define BATCH 16384

typedef __attribute__((ext_vector_type(8))) short bf16x8;
typedef __attribute__((ext_vector_type(4))) float f32x4;

#define MFMA16(a, b, c) __builtin_amdgcn_mfma_f32_16x16x32_bf16((a), (b), (c), 0, 0, 0)

// manual RNE (prep kernels — cold path)
__device__ __forceinline__ short f2bf(float f) {
  union { float f; uint32_t u; } v; v.f = f;
  return (short)((v.u + 0x7fffu + ((v.u >> 16) & 1u)) >> 16);  // RNE
}
// hot-path conversion via the HW converter (RNE, bit-identical to f2bf)
__device__ __forceinline__ short f2bf_hw(float f) {
  __hip_bfloat16 h = __float2bfloat16(f);
  union { __hip_bfloat16 h; short s; } u; u.h = h;
  return u.s;
}
__device__ __forceinline__ float frcp(float x) { return __builtin_amdgcn_rcpf(x); }
__device__ __forceinline__ float fexp2(float x) { return __builtin_amdgcn_exp2f(x); }
__device__ __forceinline__ float tanh_f(float x) {  // plain-arg tanh (for tanh(c))
  return 1.0f - 2.0f * frcp(1.0f + fexp2(2.8853900817779268f * x));
}

// ---------------- prep 0: x [B,T,9] f32 -> xbf [t][row][16] bf16 (padded) ----------------
__global__ void prep_x(const float* __restrict__ x, short* __restrict__ xbf) {
  int idx = blockIdx.x * blockDim.x + threadIdx.x;  // 0 .. B*T-1, row fastest (coalesced writes)
  int row = idx & (BATCH - 1), t = idx >> 14;
  const float* xp = x + (size_t)row * XROW + t * F_IN;
  short v[16];
#pragma unroll
  for (int j = 0; j < F_IN; ++j) v[j] = f2bf(xp[j]);
#pragma unroll
  for (int j = F_IN; j < 16; ++j) v[j] = 0;
  int4* dst = (int4*)(xbf + (size_t)idx * 16);
  dst[0] = ((const int4*)v)[0];
  dst[1] = ((const int4*)v)[1];
}

// ---------------- prep 1: W0x = Wih0 @ W_in  [512,9] -> B-frags; combined biases ----------------
__global__ void prep_w0x(const float* __restrict__ W_in, const float* __restrict__ b_in,
                         const float* __restrict__ Wih0, const float* __restrict__ bih0,
                         const float* __restrict__ bhh0, const float* __restrict__ bih1,
                         const float* __restrict__ bhh1,
                         short* __restrict__ w0xf, float* __restrict__ b0x, float* __restrict__ b1) {
  int tid = threadIdx.x;             // 0..511
  int nt = tid >> 4, hl = tid & 15;  // global ntile, col-in-tile
  int w = nt >> 2, g = nt & 3;       // wave slice, gate
  int n = g * 128 + w * 16 + hl;     // original row of Wih0 (PyTorch i,f,g,o order)
  float wacc[F_IN];
#pragma unroll
  for (int f = 0; f < F_IN; ++f) wacc[f] = 0.f;
  float bacc = 0.f;
  for (int h = 0; h < HID; ++h) {
    float wv = Wih0[n * HID + h];
    bacc += wv * b_in[h];
#pragma unroll
    for (int f = 0; f < F_IN; ++f) wacc[f] += wv * W_in[h * F_IN + f];
  }
  b0x[n] = bacc + bih0[n] + bhh0[n];
  b1[n] = bih1[n] + bhh1[n];
#pragma unroll
  for (int k = 0; k < 32; ++k) {  // one K=32 tile, f<9 real, rest zero
    int quad = k >> 3, j = k & 7;
    w0xf[((w * 4 + g) * 64 + quad * 16 + hl) * 8 + j] = (k < F_IN) ? f2bf(wacc[k]) : (short)0;
  }
}

// ---------------- prep 2: per-wave-contiguous frag layouts ----------------
__global__ void prep_wrec(const float* __restrict__ Whh0, const float* __restrict__ Wih1,
                          const float* __restrict__ Whh1,
                          short* __restrict__ whh0f, short* __restrict__ w1f) {
  int gt = blockIdx.x * blockDim.x + threadIdx.x;  // 0..6143
  if (gt < 2048) {
    int kt = gt >> 9, rr = gt & 511;
    int nt = rr >> 4, hl = rr & 15;
    int w = nt >> 2, g = nt & 3;
    int n = g * 128 + w * 16 + hl;
#pragma unroll
    for (int k = 0; k < 32; ++k) {
      int quad = k >> 3, j = k & 7;
      whh0f[((w * 16 + kt * 4 + g) * 64 + quad * 16 + hl) * 8 + j] =
          f2bf(Whh0[n * HID + kt * 32 + k]);
    }
  } else {
    int g2 = gt - 2048;
    int kt = g2 >> 9, rr = g2 & 511;  // kt 0..7: k<128 -> Wih1, else Whh1
    int nt = rr >> 4, hl = rr & 15;
    int w = nt >> 2, g = nt & 3;
    int n = g * 128 + w * 16 + hl;
#pragma unroll
    for (int k = 0; k < 32; ++k) {
      int quad = k >> 3, j = k & 7;
      int kg = kt * 32 + k;
      float v = (kg < HID) ? Wih1[n * HID + kg] : Whh1[n * HID + kg - HID];
      w1f[((w * 32 + kt * 4 + g) * 64 + quad * 16 + hl) * 8 + j] = f2bf(v);
    }
  }
}

// one full pipelined iteration at M=64: each wave computes its 64-output column slice for
// ALL 4 m-tiles, sharing each weight-fragment load across the 4 MFMAs (half the L2 weight
// stream and half the barrier count of the 2-mt/512-block shape). c-state lives in LDS
// (c1buf; c0 aliased with h1fp) to keep live regs < the hard 128-VGPR allocator cap.
// Parallel 10-trans cell (the 8-trans shared-denominator form regressed on latency).
// ROUND-22: exact r20/r21-base revert — anti-phase (r21) was falsified: duplicating the
// loop body for two phase orders pushes allocation past the 128 cap (FETCH 663 MB spill
// reloads). Pipe overlap is closed at this register budget; this is the proven floor.
__device__ __forceinline__ void lstm_step(
    int t, const short* __restrict__ xpl, const short* __restrict__ wp0,
    const short* __restrict__ wph, const short* __restrict__ wp1,
    const float* sb0, const float* sb1, float* c0buf, float* c1buf,
    const short* h0r, short* h0w, const short* h1r, short* h1w,
    int tid, int lane, int wr_off, int quad) {
  const f32x4 z4 = {0.f, 0.f, 0.f, 0.f};
  const short* xt = xpl + (size_t)t * 262144;

  // ---- phase1(t-1) MFMA: acc1 = h0_{t-1}@Wih1^T + h1_{t-2}@Whh1^T (all 4 mt) ----
  f32x4 acc1[4][4];
  {
    const short* wb = wp1;
    bf16x8 b0_ = *(const bf16x8*)(wb);
    bf16x8 b1_ = *(const bf16x8*)(wb + 512);
    bf16x8 b2_ = *(const bf16x8*)(wb + 1024);
    bf16x8 b3_ = *(const bf16x8*)(wb + 1536);
#pragma unroll
    for (int mt = 0; mt < 4; ++mt) {
      bf16x8 af = *(const bf16x8*)(h0r + ((mt * 4 + 0) * 64 + lane) * 8);
      acc1[mt][0] = MFMA16(af, b0_, z4);
      acc1[mt][1] = MFMA16(af, b1_, z4);
      acc1[mt][2] = MFMA16(af, b2_, z4);
      acc1[mt][3] = MFMA16(af, b3_, z4);
    }
  }
#pragma clang loop unroll_count(3)
  for (int kt = 1; kt < 4; ++kt) {  // rest of Wih1, A = h0_{t-1}
    const short* wb = wp1 + kt * 2048;
    bf16x8 b0_ = *(const bf16x8*)(wb);
    bf16x8 b1_ = *(const bf16x8*)(wb + 512);
    bf16x8 b2_ = *(const bf16x8*)(wb + 1024);
    bf16x8 b3_ = *(const bf16x8*)(wb + 1536);
#pragma unroll
    for (int mt = 0; mt < 4; ++mt) {
      bf16x8 af = *(const bf16x8*)(h0r + ((mt * 4 + kt) * 64 + lane) * 8);
      acc1[mt][0] = MFMA16(af, b0_, acc1[mt][0]);
      acc1[mt][1] = MFMA16(af, b1_, acc1[mt][1]);
      acc1[mt][2] = MFMA16(af, b2_, acc1[mt][2]);
      acc1[mt][3] = MFMA16(af, b3_, acc1[mt][3]);
    }
  }
#pragma clang loop unroll_count(2)
  for (int kt = 0; kt < 4; ++kt) {  // Whh1, A = h1_{t-2}
    const short* wb = wp1 + (kt + 4) * 2048;
    bf16x8 b0_ = *(const bf16x8*)(wb);
    bf16x8 b1_ = *(const bf16x8*)(wb + 512);
    bf16x8 b2_ = *(const bf16x8*)(wb + 1024);
    bf16x8 b3_ = *(const bf16x8*)(wb + 1536);
#pragma unroll
    for (int mt = 0; mt < 4; ++mt) {
      bf16x8 af = *(const bf16x8*)(h1r + ((mt * 4 + kt) * 64 + lane) * 8);
      acc1[mt][0] = MFMA16(af, b0_, acc1[mt][0]);
      acc1[mt][1] = MFMA16(af, b1_, acc1[mt][1]);
      acc1[mt][2] = MFMA16(af, b2_, acc1[mt][2]);
      acc1[mt][3] = MFMA16(af, b3_, acc1[mt][3]);
    }
  }
  // cell 1 (for step t-1): c1 state in LDS, one b128 read + write per mt
#pragma unroll
  for (int mt = 0; mt < 4; ++mt) {
    f32x4 cp = *(const f32x4*)(c1buf + 4 * (mt * 512 + tid));
    f32x4 cn;
#pragma unroll
    for (int r = 0; r < 4; ++r) {
      float gi = frcp(1.0f + fexp2(fmaf(-1.4426950408889634f, acc1[mt][0][r], sb1[0])));
      float gf = frcp(1.0f + fexp2(fmaf(-1.4426950408889634f, acc1[mt][1][r], sb1[1])));
      float gg = 1.0f - 2.0f * frcp(1.0f + fexp2(fmaf(2.8853900817779268f, acc1[mt][2][r], sb1[2])));
      float go = frcp(1.0f + fexp2(fmaf(-1.4426950408889634f, acc1[mt][3][r], sb1[3])));
      cn[r] = gf * cp[r] + gi * gg;
      float hn = go * tanh_f(cn[r]);
      h1w[mt * 2048 + r * 8 + wr_off] = f2bf_hw(hn);
    }
    *(f32x4*)(c1buf + 4 * (mt * 512 + tid)) = cn;
  }
  // ---- phase0(t): acc0 = x_t@W0x^T + h0_{t-1}@Whh0^T (all 4 mt) ----
  f32x4 acc0[4][4];
  {
    bf16x8 b0_ = *(const bf16x8*)(wp0);
    bf16x8 b1_ = *(const bf16x8*)(wp0 + 512);
    bf16x8 b2_ = *(const bf16x8*)(wp0 + 1024);
    bf16x8 b3_ = *(const bf16x8*)(wp0 + 1536);
#pragma unroll
    for (int mt = 0; mt < 4; ++mt) {
      bf16x8 xf = {0, 0, 0, 0, 0, 0, 0, 0};
      if (quad < 2) xf = *(const bf16x8*)(xt + mt * 256);
      acc0[mt][0] = MFMA16(xf, b0_, z4);
      acc0[mt][1] = MFMA16(xf, b1_, z4);
      acc0[mt][2] = MFMA16(xf, b2_, z4);
      acc0[mt][3] = MFMA16(xf, b3_, z4);
    }
  }
#pragma clang loop unroll_count(2)
  for (int kt = 0; kt < 4; ++kt) {
    const short* wb = wph + kt * 2048;
    bf16x8 b0_ = *(const bf16x8*)(wb);
    bf16x8 b1_ = *(const bf16x8*)(wb + 512);
    bf16x8 b2_ = *(const bf16x8*)(wb + 1024);
    bf16x8 b3_ = *(const bf16x8*)(wb + 1536);
#pragma unroll
    for (int mt = 0; mt < 4; ++mt) {
      bf16x8 af = *(const bf16x8*)(h0r + ((mt * 4 + kt) * 64 + lane) * 8);
      acc0[mt][0] = MFMA16(af, b0_, acc0[mt][0]);
      acc0[mt][1] = MFMA16(af, b1_, acc0[mt][1]);
      acc0[mt][2] = MFMA16(af, b2_, acc0[mt][2]);
      acc0[mt][3] = MFMA16(af, b3_, acc0[mt][3]);
    }
  }
  // cell 0: c0 state in LDS (c0buf aliases h1fp — c0 dies exactly when h1fp is born)
#pragma unroll
  for (int mt = 0; mt < 4; ++mt) {
    f32x4 cp = *(const f32x4*)(c0buf + 4 * (mt * 512 + tid));
    f32x4 cn;
#pragma unroll
    for (int r = 0; r < 4; ++r) {
      float gi = frcp(1.0f + fexp2(fmaf(-1.4426950408889634f, acc0[mt][0][r], sb0[0])));
      float gf = frcp(1.0f + fexp2(fmaf(-1.4426950408889634f, acc0[mt][1][r], sb0[1])));
      float gg = 1.0f - 2.0f * frcp(1.0f + fexp2(fmaf(2.8853900817779268f, acc0[mt][2][r], sb0[2])));
      float go = frcp(1.0f + fexp2(fmaf(-1.4426950408889634f, acc0[mt][3][r], sb0[3])));
      cn[r] = gf * cp[r] + gi * gg;
      float hn = go * tanh_f(cn[r]);
      h0w[mt * 2048 + r * 8 + wr_off] = f2bf_hw(hn);
    }
    *(f32x4*)(c0buf + 4 * (mt * 512 + tid)) = cn;
  }
  __syncthreads();  // the ONE barrier: publishes h0_t and h1_{t-1}
}

// ---------------- main: 256 blocks x 512 thr, M=64/block (ONE round) ----------------
// Established facts: 512-thr + no attribute -> allocator follows LDS model (124 regs,
// no spill); occupancy fixed at 2 waves/SIMD; LDS 134144 B -> 1-WG compiler model.
__global__ void __launch_bounds__(512)
lstm_main(const short* __restrict__ xbf, const short* __restrict__ w0xf,
          const short* __restrict__ whh0f, const short* __restrict__ w1f,
          const float* __restrict__ b0x, const float* __restrict__ b1,
          const float* __restrict__ Wout, const float* __restrict__ bout,
          float* __restrict__ out) {
  // Each h buffer: [4 mt][4 kt][64 lane][8] shorts = 8192 shorts (16 KB).
  __shared__ short h0a[8192], h0b[8192], h1a[8192], h1b[8192];  // 64 KB
  __shared__ float h1fp_c0[64 * HID];  // 32 KB: c0 state during loop, fp32 h1 at drain
  __shared__ float c1buf[64 * HID];    // 32 KB: c1 state [mt][tid] f32x4
  __shared__ float lg[64 * OUT_N];     // 3 KB logits
  // total LDS = 134144 B

  const int tid = threadIdx.x;
  const int w = tid >> 6, lane = tid & 63;   // w = wave id = weight/column slice 0..7
  const int quad = lane >> 4, c = lane & 15;
  const int rowbase = blockIdx.x * 64;

  {  // zero h buffers and c-state (h_{-1} = h_{-2} = c_{-1} = 0)
    for (int i = tid; i < 4096; i += 512) {
      ((int*)h0a)[i] = 0; ((int*)h0b)[i] = 0; ((int*)h1a)[i] = 0; ((int*)h1b)[i] = 0;
    }
    for (int i = tid; i < 8192; i += 512) { h1fp_c0[i] = 0.f; c1buf[i] = 0.f; }
  }

  // per-wave weight stream bases (t-invariant, lane offset folded in)
  const short* wp0 = w0xf + (w * 4) * 512 + lane * 8;    // 4 frags, stride 512 shorts
  const short* wph = whh0f + (w * 16) * 512 + lane * 8;  // 16 frags
  const short* wp1 = w1f + (w * 32) * 512 + lane * 8;    // 32 frags

  // x frag pointer: addr(t,mt) = ((t*16384 + rowbase + mt*16 + c) * 16 + (quad&1)*8) shorts
  const short* xpl = xbf + ((size_t)(rowbase + c) << 4) + ((quad & 1) << 3);

  // pre-scaled biases: gates i,f,o -> -1.4427*b (sigm); gate g(idx 2) -> +2.8854*b (tanh)
  float sb0[4], sb1[4];
#pragma unroll
  for (int g = 0; g < 4; ++g) {
    int n = g * 128 + w * 16 + c;
    float bv0 = b0x[n], bv1 = b1[n];
    sb0[g] = (g == 2) ? 2.8853900817779268f * bv0 : -1.4426950408889634f * bv0;
    sb1[g] = (g == 2) ? 2.8853900817779268f * bv1 : -1.4426950408889634f * bv1;
  }

  // writer constants: this lane's h column is hcol = w*16 + c
  const int kt_w = w >> 1;
  const int klocal = ((w & 1) << 4) + c;
  const int quadA = klocal >> 3;
  const int jA = klocal & 7;
  const int wr_off = (kt_w * 64 + quadA * 16 + quad * 4) * 8 + jA;  // + mt*2048 + r*8

  const f32x4 z4 = {0.f, 0.f, 0.f, 0.f};

  __syncthreads();

  // ================= prologue: phase0(t=0) -> h0a =================
  {
    f32x4 acc[4][4];
    {
      bf16x8 b0_ = *(const bf16x8*)(wp0);
      bf16x8 b1_ = *(const bf16x8*)(wp0 + 512);
      bf16x8 b2_ = *(const bf16x8*)(wp0 + 1024);
      bf16x8 b3_ = *(const bf16x8*)(wp0 + 1536);
#pragma unroll
      for (int mt = 0; mt < 4; ++mt) {
        bf16x8 xf = {0, 0, 0, 0, 0, 0, 0, 0};
        if (quad < 2) xf = *(const bf16x8*)(xpl + mt * 256);
        acc[mt][0] = MFMA16(xf, b0_, z4);
        acc[mt][1] = MFMA16(xf, b1_, z4);
        acc[mt][2] = MFMA16(xf, b2_, z4);
        acc[mt][3] = MFMA16(xf, b3_, z4);
      }
    }
    // h0_{-1} = 0: whh0 contribution is zero — skip the 4 kt groups entirely.
#pragma unroll
    for (int mt = 0; mt < 4; ++mt) {
      f32x4 cn;
#pragma unroll
      for (int r = 0; r < 4; ++r) {
        float gi = frcp(1.0f + fexp2(fmaf(-1.4426950408889634f, acc[mt][0][r], sb0[0])));
        float gg = 1.0f - 2.0f * frcp(1.0f + fexp2(fmaf(2.8853900817779268f, acc[mt][2][r], sb0[2])));
        float go = frcp(1.0f + fexp2(fmaf(-1.4426950408889634f, acc[mt][3][r], sb0[3])));
        cn[r] = gi * gg;  // c0_{-1} = 0
        float hn = go * tanh_f(cn[r]);
        h0a[mt * 2048 + r * 8 + wr_off] = f2bf_hw(hn);
      }
      *(f32x4*)(h1fp_c0 + 4 * (mt * 512 + tid)) = cn;
    }
  }
  __syncthreads();

  // ================= main loop: 63 static pairs + 1 tail ==========
  // parity: odd t reads {h0a,h1a} writes {h0b,h1b}; even t reads {h0b,h1b} writes {h0a,h1a}
#pragma clang loop unroll(disable)
  for (int t = 1; t < 127; t += 2) {
    lstm_step(t,     xpl, wp0, wph, wp1, sb0, sb1, h1fp_c0, c1buf, h0a, h0b, h1a, h1b,
              tid, lane, wr_off, quad);
    lstm_step(t + 1, xpl, wp0, wph, wp1, sb0, sb1, h1fp_c0, c1buf, h0b, h0a, h1b, h1a,
              tid, lane, wr_off, quad);
  }
  lstm_step(127, xpl, wp0, wph, wp1, sb0, sb1, h1fp_c0, c1buf, h0a, h0b, h1a, h1b,
            tid, lane, wr_off, quad);

  // ================= drain: phase1(t=127) -> fp32 h1 straight to LDS =================
  // after the tail step: h0b = h0(127), h1b = h1(126); c0 state is dead from here on,
  // so h1fp_c0 is reused as the fp32 h1 staging buffer.
  {
    f32x4 acc[4][4];
    {
      const short* wb = wp1;
      bf16x8 b0_ = *(const bf16x8*)(wb);
      bf16x8 b1_ = *(const bf16x8*)(wb + 512);
      bf16x8 b2_ = *(const bf16x8*)(wb + 1024);
      bf16x8 b3_ = *(const bf16x8*)(wb + 1536);
#pragma unroll
      for (int mt = 0; mt < 4; ++mt) {
        bf16x8 af = *(const bf16x8*)(h0b + ((mt * 4 + 0) * 64 + lane) * 8);
        acc[mt][0] = MFMA16(af, b0_, z4);
        acc[mt][1] = MFMA16(af, b1_, z4);
        acc[mt][2] = MFMA16(af, b2_, z4);
        acc[mt][3] = MFMA16(af, b3_, z4);
      }
    }
#pragma unroll
    for (int kt = 1; kt < 4; ++kt) {
      const short* wb = wp1 + kt * 2048;
      bf16x8 b0_ = *(const bf16x8*)(wb);
      bf16x8 b1_ = *(const bf16x8*)(wb + 512);
      bf16x8 b2_ = *(const bf16x8*)(wb + 1024);
      bf16x8 b3_ = *(const bf16x8*)(wb + 1536);
#pragma unroll
      for (int mt = 0; mt < 4; ++mt) {
        bf16x8 af = *(const bf16x8*)(h0b + ((mt * 4 + kt) * 64 + lane) * 8);
        acc[mt][0] = MFMA16(af, b0_, acc[mt][0]);
        acc[mt][1] = MFMA16(af, b1_, acc[mt][1]);
        acc[mt][2] = MFMA16(af, b2_, acc[mt][2]);
        acc[mt][3] = MFMA16(af, b3_, acc[mt][3]);
      }
    }
#pragma unroll
    for (int kt = 0; kt < 4; ++kt) {
      const short* wb = wp1 + (kt + 4) * 2048;
      bf16x8 b0_ = *(const bf16x8*)(wb);
      bf16x8 b1_ = *(const bf16x8*)(wb + 512);
      bf16x8 b2_ = *(const bf16x8*)(wb + 1024);
      bf16x8 b3_ = *(const bf16x8*)(wb + 1536);
#pragma unroll
      for (int mt = 0; mt < 4; ++mt) {
        bf16x8 af = *(const bf16x8*)(h1b + ((mt * 4 + kt) * 64 + lane) * 8);
        acc[mt][0] = MFMA16(af, b0_, acc[mt][0]);
        acc[mt][1] = MFMA16(af, b1_, acc[mt][1]);
        acc[mt][2] = MFMA16(af, b2_, acc[mt][2]);
        acc[mt][3] = MFMA16(af, b3_, acc[mt][3]);
      }
    }
    __syncthreads();  // all c0 reads done before h1fp overwrites
#pragma unroll
    for (int mt = 0; mt < 4; ++mt) {
      f32x4 cp = *(const f32x4*)(c1buf + 4 * (mt * 512 + tid));
#pragma unroll
      for (int r = 0; r < 4; ++r) {
        float gi = frcp(1.0f + fexp2(fmaf(-1.4426950408889634f, acc[mt][0][r], sb1[0])));
        float gf = frcp(1.0f + fexp2(fmaf(-1.4426950408889634f, acc[mt][1][r], sb1[1])));
        float gg = 1.0f - 2.0f * frcp(1.0f + fexp2(fmaf(2.8853900817779268f, acc[mt][2][r], sb1[2])));
        float go = frcp(1.0f + fexp2(fmaf(-1.4426950408889634f, acc[mt][3][r], sb1[3])));
        float cn = gf * cp[r] + gi * gg;
        float hn = go * tanh_f(cn);
        h1fp_c0[(mt * 16 + quad * 4 + r) * HID + w * 16 + c] = hn;
      }
    }
  }
  __syncthreads();  // h1fp complete before epilogue reads

  // ================= epilogue: logits = h1 @ Wout^T + bout, softmax over 12 =================
  {
    int row = tid >> 3, og = tid & 7;  // 64 rows x 8 threads
    for (int oc = og; oc < OUT_N; oc += 8) {
      float s = bout[oc];
      const float* wo = Wout + oc * HID;
      const float* hr = h1fp_c0 + row * HID;
#pragma unroll 8
      for (int k = 0; k < HID; ++k) s += hr[k] * wo[k];
      lg[row * OUT_N + oc] = s;
    }
  }
  __syncthreads();
  if (tid < 64) {
    int row = tid;
    float m = lg[row * OUT_N];
#pragma unroll
    for (int oc = 1; oc < OUT_N; ++oc) m = fmaxf(m, lg[row * OUT_N + oc]);
    float e[OUT_N];
    float s = 0.f;
#pragma unroll
    for (int oc = 0; oc < OUT_N; ++oc) {
      e[oc] = __expf(lg[row * OUT_N + oc] - m);
      s += e[oc];
    }
    float inv = 1.0f / s;
    float* orow = out + (size_t)(rowbase + row) * OUT_N;
#pragma unroll
    for (int oc = 0; oc < OUT_N; ++oc) orow[oc] = e[oc] * inv;
  }
}

extern "C" void kernel_launch(void* const* d_in, const int* in_sizes, int n_in,
                              void* d_out, int out_size, void* d_ws, size_t ws_size,
                              hipStream_t stream) {
  const float* x    = (const float*)d_in[0];
  const float* W_in = (const float*)d_in[1];
  const float* b_in = (const float*)d_in[2];
  const float* Wih0 = (const float*)d_in[3];
  const float* Whh0 = (const float*)d_in[4];
  const float* bih0 = (const float*)d_in[5];
  const float* bhh0 = (const float*)d_in[6];
  const float* Wih1 = (const float*)d_in[7];
  const float* Whh1 = (const float*)d_in[8];
  const float* bih1 = (const float*)d_in[9];
  const float* bhh1 = (const float*)d_in[10];
  const float* Wout = (const float*)d_in[11];
  const float* bout = (const float*)d_in[12];
  float* out = (float*)d_out;

  // workspace layout: frag-packed bf16 weights + combined biases (~420 KB) + xbf (64 MB)
  short* w0xf  = (short*)d_ws;            // 16384 shorts (32 KB)
  short* whh0f = w0xf + 16384;            // 65536 shorts (128 KB)
  short* w1f   = whh0f + 65536;           // 131072 shorts (256 KB)
  float* b0x   = (float*)(w1f + 131072);  // 512 f32
  float* b1    = b0x + 512;               // 512 f32
  short* xbf   = (short*)(b1 + 512);      // B*T*16 shorts = 64 MiB, 32B-aligned

  prep_x<<<(BATCH * T_STEPS) / 256, 256, 0, stream>>>(x, xbf);
  prep_w0x<<<1, 512, 0, stream>>>(W_in, b_in, Wih0, bih0, bhh0, bih1, bhh1, w0xf, b0x, b1);
  prep_wrec<<<12, 512, 0, stream>>>(Whh0, Wih1, Whh1, whh0f, w1f);
  lstm_main<<<256, 512, 0, stream>>>(xbf, w0xf, whh0f, w1f, b0x, b1, Wout, bout, out);
}